// Round 4
// baseline (1016.190 us; speedup 1.0000x reference)
//
#include <hip/hip_runtime.h>

typedef short v8s __attribute__((ext_vector_type(8)));
typedef float v4f __attribute__((ext_vector_type(4)));

__device__ __forceinline__ unsigned short f2bf(float f) {
  union { float f; unsigned u; } x; x.f = f;
  unsigned r = x.u + 0x7fffu + ((x.u >> 16) & 1u);
  return (unsigned short)(r >> 16);
}

__device__ __forceinline__ void cvt16(const float* __restrict__ src, unsigned short* dst) {
  const float4* p = (const float4*)src;
  float4 a = p[0], b = p[1], c = p[2], d = p[3];
  dst[0] = f2bf(a.x);  dst[1] = f2bf(a.y);  dst[2] = f2bf(a.z);  dst[3] = f2bf(a.w);
  dst[4] = f2bf(b.x);  dst[5] = f2bf(b.y);  dst[6] = f2bf(b.z);  dst[7] = f2bf(b.w);
  dst[8] = f2bf(c.x);  dst[9] = f2bf(c.y);  dst[10] = f2bf(c.z); dst[11] = f2bf(c.w);
  dst[12] = f2bf(d.x); dst[13] = f2bf(d.y); dst[14] = f2bf(d.z); dst[15] = f2bf(d.w);
}

// =====================================================================
// GEMM: C[M,512] = A[M,512] @ W[512,512]^T   (BM=BN=128, BK=32, 4 waves)
// MODE 0: A = fp32 (x rows [0,rows0) then support), C = bf16, Q-rows scaled.
// MODE 1: A = bf16 (OT flat), C = fp32 + bias.
// =====================================================================
template <int MODE>
__launch_bounds__(256)
__global__ void gemm_bt_kernel(const float* __restrict__ A0,
                               const float* __restrict__ A1, int rows0,
                               const unsigned short* __restrict__ Abf,
                               const float* __restrict__ Wsrc,
                               const float* __restrict__ bias,
                               unsigned short* __restrict__ Cb,
                               float* __restrict__ Cf, float scale) {
  __shared__ __align__(16) char smem[(MODE == 1) ? 65536 : 32768];
  const int tid = threadIdx.x;
  const int wave = tid >> 6, lane = tid & 63, lr = lane & 15, lg = lane >> 4;
  const int mb = blockIdx.x >> 2, nb = blockIdx.x & 3;
  const int wr = wave >> 1, wc = wave & 1;

  v4f acc[4][4];
#pragma unroll
  for (int i = 0; i < 4; ++i)
#pragma unroll
    for (int j = 0; j < 4; ++j) acc[i][j] = (v4f){0.f, 0.f, 0.f, 0.f};

  const int srow = tid >> 1, kh = tid & 1;
  const size_t arow = (size_t)mb * 128 + srow;
  const float* asrcf = nullptr;
  const unsigned short* asrcb = nullptr;
  if constexpr (MODE == 0) {
    asrcf = (arow < (size_t)rows0) ? (A0 + arow * 512) : (A1 + (arow - (size_t)rows0) * 512);
  } else {
    asrcb = Abf + arow * 512;
  }
  const float* bsrcf = Wsrc + ((size_t)nb * 128 + srow) * 512;
  const int wa0 = srow * 64 + ((kh * 32) ^ ((srow & 3) << 4));
  const int wa1 = srow * 64 + (((kh * 32) + 16) ^ ((srow & 3) << 4));

  for (int kt = 0; kt < 16; ++kt) {
    const int kbase = kt * 32 + kh * 16;
    __syncthreads();
    unsigned short ta[16], tb[16];
    if constexpr (MODE == 0) {
      cvt16(asrcf + kbase, ta);
    } else {
      const v8s* ap = (const v8s*)(asrcb + kbase);
      *(v8s*)&ta[0] = ap[0];
      *(v8s*)&ta[8] = ap[1];
    }
    cvt16(bsrcf + kbase, tb);
    *(v8s*)&smem[wa0] = *(const v8s*)&ta[0];
    *(v8s*)&smem[wa1] = *(const v8s*)&ta[8];
    *(v8s*)&smem[8192 + wa0] = *(const v8s*)&tb[0];
    *(v8s*)&smem[8192 + wa1] = *(const v8s*)&tb[8];
    __syncthreads();

    v8s af[4], bfr[4];
    const int fo = (lg * 16) ^ ((lr & 3) << 4);
#pragma unroll
    for (int mi = 0; mi < 4; ++mi)
      af[mi] = *(const v8s*)&smem[(wr * 64 + mi * 16 + lr) * 64 + fo];
#pragma unroll
    for (int ni = 0; ni < 4; ++ni)
      bfr[ni] = *(const v8s*)&smem[8192 + (wc * 64 + ni * 16 + lr) * 64 + fo];
#pragma unroll
    for (int mi = 0; mi < 4; ++mi)
#pragma unroll
      for (int ni = 0; ni < 4; ++ni)
        acc[mi][ni] = __builtin_amdgcn_mfma_f32_16x16x32_bf16(bfr[ni], af[mi], acc[mi][ni], 0, 0, 0);
  }

  __syncthreads();
  if constexpr (MODE == 0) {
#pragma unroll
    for (int mi = 0; mi < 4; ++mi) {
      const int ml = wr * 64 + mi * 16 + lr;
      const float sc = ((size_t)mb * 128 + ml < (size_t)rows0) ? scale : 1.0f;
#pragma unroll
      for (int ni = 0; ni < 4; ++ni) {
        const int nl = wc * 64 + ni * 16 + lg * 4;
        ushort4 pk;
        pk.x = f2bf(acc[mi][ni][0] * sc);
        pk.y = f2bf(acc[mi][ni][1] * sc);
        pk.z = f2bf(acc[mi][ni][2] * sc);
        pk.w = f2bf(acc[mi][ni][3] * sc);
        *(ushort4*)&smem[ml * 256 + ((nl * 2) ^ ((ml & 7) << 4))] = pk;
      }
    }
    __syncthreads();
#pragma unroll
    for (int p = 0; p < 8; ++p) {
      const int row = p * 16 + (tid >> 4);
      const int off = (tid & 15) * 16;
      v8s v = *(const v8s*)&smem[row * 256 + (off ^ ((row & 7) << 4))];
      *(v8s*)(Cb + ((size_t)mb * 128 + row) * 512 + nb * 128 + (tid & 15) * 8) = v;
    }
  } else {
#pragma unroll
    for (int mi = 0; mi < 4; ++mi) {
      const int ml = wr * 64 + mi * 16 + lr;
#pragma unroll
      for (int ni = 0; ni < 4; ++ni) {
        const int nl = wc * 64 + ni * 16 + lg * 4;
        *(float4*)&smem[ml * 512 + ((nl * 4) ^ ((ml & 7) << 4))] =
            (float4){acc[mi][ni][0], acc[mi][ni][1], acc[mi][ni][2], acc[mi][ni][3]};
      }
    }
    __syncthreads();
    const float4 bb = *(const float4*)(bias + nb * 128 + (tid & 31) * 4);
#pragma unroll
    for (int p = 0; p < 16; ++p) {
      const int row = p * 8 + (tid >> 5);
      const int off = (tid & 31) * 16;
      float4 v = *(const float4*)&smem[row * 512 + (off ^ ((row & 7) << 4))];
      v.x += bb.x; v.y += bb.y; v.z += bb.z; v.w += bb.w;
      *(float4*)(Cf + ((size_t)mb * 128 + row) * 512 + nb * 128 + (tid & 31) * 4) = v;
    }
  }
}

// =====================================================================
// Transpose: Kb [B*4096,512] bf16 -> KT [B][512][4096] bf16, with the
// post-softmax key mask folded in (KT is only used as V; zeroing V rows
// for masked keys == zeroing P columns, and lsum stays unmasked per ref).
// =====================================================================
__global__ __launch_bounds__(256) void transpose_k(const unsigned short* __restrict__ Kb,
                                                   const int* __restrict__ amask,
                                                   unsigned short* __restrict__ KT) {
  __shared__ unsigned short tile[64][65];
  const int b = blockIdx.z, cb = blockIdx.y * 64, mb = blockIdx.x * 64;
  const int tid = threadIdx.x;
#pragma unroll
  for (int i = 0; i < 16; ++i) {
    const int e = i * 256 + tid;
    const int ml = e >> 6, cl = e & 63;
    tile[ml][cl] = Kb[((size_t)b * 4096 + mb + ml) * 512 + cb + cl];
  }
  __syncthreads();
#pragma unroll
  for (int i = 0; i < 16; ++i) {
    const int e = i * 256 + tid;
    const int cl = e >> 6, ml = e & 63;
    const unsigned short v = amask[mb + ml] ? tile[ml][cl] : (unsigned short)0;
    KT[((size_t)b * 512 + cb + cl) * 4096 + mb + ml] = v;
  }
}

// =====================================================================
// Flash attention v4: 32 q/block, 4 waves, grid 512 (2 blocks/CU).
// QK role: wave (qh=w&1, kh=w>>1) computes S quadrant [16q x 16k].
// PV role: wave w accumulates o[32 q][c-slice w*128..+128] (64 regs).
// Cross-wave softmax via LDS Mpart/Lpart; all waves track mrun/lsum for
// all 32 q (identical state). Deferred rescale THR=8. 4 barriers/iter.
// LDS: K 32KB @0, VT 32KB @32768, P 2KB @65536, M @67584, L @67840.
// =====================================================================
__launch_bounds__(256, 2)
__global__ void attn_kernel(const unsigned short* __restrict__ Qb,
                            const unsigned short* __restrict__ Kall,
                            const unsigned short* __restrict__ KT,
                            unsigned short* __restrict__ OT) {
  __shared__ __align__(16) char smem[68608];
  const int tid = threadIdx.x, wave = tid >> 6, lane = tid & 63;
  const int lr = lane & 15, lg = lane >> 4;
  const int qh = wave & 1, kh = wave >> 1;
  const int orig = (blockIdx.x & 7) * 64 + (blockIdx.x >> 3);  // XCD-chunked
  const int b = orig >> 7;
  const int qb0 = (orig & 127) * 32;
  constexpr int Pb = 65536, Mb = 67584, Lb = 67840;

  const unsigned short* Kbb = Kall + (size_t)b * 4096 * 512;
  const unsigned short* KTb = KT + (size_t)b * 512 * 4096;

  // Q frags: rows q = qb0 + qh*16 + lr
  const unsigned short* Qrow = Qb + ((size_t)b * 4096 + qb0 + qh * 16 + lr) * 512;
  v8s qf[16];
#pragma unroll
  for (int cs = 0; cs < 16; ++cs) qf[cs] = *(const v8s*)(Qrow + cs * 32 + lg * 8);

  v4f o[2][8];
#pragma unroll
  for (int i = 0; i < 2; ++i)
#pragma unroll
    for (int j = 0; j < 8; ++j) o[i][j] = (v4f){0.f, 0.f, 0.f, 0.f};
  float mrun[2][4], lsum[2][4];
#pragma unroll
  for (int i = 0; i < 2; ++i)
#pragma unroll
    for (int r = 0; r < 4; ++r) { mrun[i][r] = -3e38f; lsum[i][r] = 0.f; }

#pragma unroll 1
  for (int it = 0; it < 128; ++it) {
    const int kb = it * 32;
    __syncthreads();  // A: prev-iter tile/P reads complete
    // ---- stage K tile [32 keys][1KB], swizzled by key&7
#pragma unroll
    for (int i = 0; i < 8; ++i) {
      const int ci = i * 256 + tid;
      const int key = ci >> 6, s16 = ci & 63;
      v8s v = *(const v8s*)(Kbb + (size_t)(kb + key) * 512 + s16 * 8);
      *(v8s*)&smem[key * 1024 + ((s16 * 16) ^ ((key & 7) << 4))] = v;
    }
    // ---- stage VT tile [512 c][64B], swizzled by (c>>1)&3
#pragma unroll
    for (int i = 0; i < 8; ++i) {
      const int ci = i * 256 + tid;
      const int c = ci >> 2, sq = ci & 3;
      v8s v = *(const v8s*)(KTb + (size_t)c * 4096 + kb + sq * 8);
      *(v8s*)&smem[32768 + c * 64 + ((sq * 16) ^ (((c >> 1) & 3) << 4))] = v;
    }
    __syncthreads();  // B: tiles ready

    // ---- QK quadrant: q rows qh*16+(lg*4+r), keys kh*16+lr
    v4f se = (v4f){0.f, 0.f, 0.f, 0.f}, so = (v4f){0.f, 0.f, 0.f, 0.f};
    const int krow = kh * 16 + lr;
    const int kswz = (krow & 7) << 4;
    __builtin_amdgcn_s_setprio(1);
#pragma unroll
    for (int cs = 0; cs < 16; cs += 2) {
      v8s k0 = *(const v8s*)&smem[krow * 1024 + ((cs * 64 + lg * 16) ^ kswz)];
      v8s k1 = *(const v8s*)&smem[krow * 1024 + (((cs + 1) * 64 + lg * 16) ^ kswz)];
      se = __builtin_amdgcn_mfma_f32_16x16x32_bf16(qf[cs], k0, se, 0, 0, 0);
      so = __builtin_amdgcn_mfma_f32_16x16x32_bf16(qf[cs + 1], k1, so, 0, 0, 0);
    }
    __builtin_amdgcn_s_setprio(0);
    v4f s = se + so;

    // ---- partial rowmax over this quadrant's 16 keys
    float tm[4];
#pragma unroll
    for (int r = 0; r < 4; ++r) tm[r] = s[r];
#pragma unroll
    for (int msk = 1; msk < 16; msk <<= 1)
#pragma unroll
      for (int r = 0; r < 4; ++r) tm[r] = fmaxf(tm[r], __shfl_xor(tm[r], msk));
    if (lr == 0) {
#pragma unroll
      for (int r = 0; r < 4; ++r)
        *(float*)&smem[Mb + (qh * 16 + lg * 4 + r) * 8 + kh * 4] = tm[r];
    }
    __syncthreads();  // C: Mpart ready

    // ---- all waves: combined max, deferred rescale (identical state)
    float pm[2][4];
#pragma unroll
    for (int q2 = 0; q2 < 2; ++q2)
#pragma unroll
      for (int r = 0; r < 4; ++r) {
        const float2 mm = *(const float2*)&smem[Mb + (q2 * 16 + lg * 4 + r) * 8];
        pm[q2][r] = fmaxf(mm.x, mm.y);
      }
    bool need = false;
#pragma unroll
    for (int q2 = 0; q2 < 2; ++q2)
#pragma unroll
      for (int r = 0; r < 4; ++r) need = need || (pm[q2][r] > mrun[q2][r] + 8.0f);
    if (__any(need)) {
#pragma unroll
      for (int q2 = 0; q2 < 2; ++q2) {
        v4f sfv;
#pragma unroll
        for (int r = 0; r < 4; ++r) {
          const float nm = fmaxf(mrun[q2][r], pm[q2][r]);
          const float sf = __expf(mrun[q2][r] - nm);
          lsum[q2][r] *= sf;
          mrun[q2][r] = nm;
          sfv[r] = sf;
        }
#pragma unroll
        for (int ct = 0; ct < 8; ++ct) o[q2][ct] *= sfv;
      }
    }

    // ---- p = exp(s - mrun) (unmasked; V pre-masked in KT), P + Lpart
    float lp[4];
#pragma unroll
    for (int r = 0; r < 4; ++r) {
      const int q = qh * 16 + lg * 4 + r;
      const float p = __expf(s[r] - mrun[qh][r]);
      lp[r] = p;
      *(unsigned short*)&smem[Pb + q * 64 + ((kh * 32 + lr * 2) ^ (((q >> 1) & 3) << 4))] =
          f2bf(p);
    }
#pragma unroll
    for (int msk = 1; msk < 16; msk <<= 1)
#pragma unroll
      for (int r = 0; r < 4; ++r) lp[r] += __shfl_xor(lp[r], msk);
    if (lr == 0) {
#pragma unroll
      for (int r = 0; r < 4; ++r)
        *(float*)&smem[Lb + (qh * 16 + lg * 4 + r) * 8 + kh * 4] = lp[r];
    }
    __syncthreads();  // D: P/Lpart ready

#pragma unroll
    for (int q2 = 0; q2 < 2; ++q2)
#pragma unroll
      for (int r = 0; r < 4; ++r) {
        const float2 ll = *(const float2*)&smem[Lb + (q2 * 16 + lg * 4 + r) * 8];
        lsum[q2][r] += ll.x + ll.y;
      }

    // ---- PV: o[q2][ct] over c-slice wave*128
    __builtin_amdgcn_s_setprio(1);
#pragma unroll
    for (int q2 = 0; q2 < 2; ++q2) {
      const int prow = q2 * 16 + lr;
      v8s pf = *(const v8s*)&smem[Pb + prow * 64 + ((lg * 16) ^ (((prow >> 1) & 3) << 4))];
#pragma unroll
      for (int ct = 0; ct < 8; ++ct) {
        const int c = wave * 128 + ct * 16 + lr;
        v8s vf = *(const v8s*)&smem[32768 + c * 64 + ((lg * 16) ^ (((c >> 1) & 3) << 4))];
        o[q2][ct] = __builtin_amdgcn_mfma_f32_16x16x32_bf16(pf, vf, o[q2][ct], 0, 0, 0);
      }
    }
    __builtin_amdgcn_s_setprio(0);
  }

  // ---- epilogue: normalize, bounce [128 c][32 q] per wave, store OT
  float inv[2][4];
#pragma unroll
  for (int q2 = 0; q2 < 2; ++q2)
#pragma unroll
    for (int r = 0; r < 4; ++r) inv[q2][r] = 1.0f / lsum[q2][r];

  __syncthreads();
#pragma unroll
  for (int q2 = 0; q2 < 2; ++q2)
#pragma unroll
    for (int ct = 0; ct < 8; ++ct)
#pragma unroll
      for (int r = 0; r < 4; ++r) {
        const int cl = ct * 16 + lr;
        const int qq = q2 * 16 + lg * 4 + r;
        *(unsigned short*)&smem[wave * 8192 + cl * 64 + ((qq * 2) ^ ((cl & 3) << 4))] =
            f2bf(o[q2][ct][r] * inv[q2][r]);
      }
  __syncthreads();
  unsigned short* OTb = OT + (size_t)b * 512 * 4096 + qb0;
#pragma unroll
  for (int i = 0; i < 8; ++i) {
    const int idx = i * 256 + tid;
    const int c = idx >> 2, qc = idx & 3;
    const int cl = c & 127, w2 = c >> 7;
    v8s v = *(const v8s*)&smem[w2 * 8192 + cl * 64 + ((qc * 16) ^ ((cl & 3) << 4))];
    *(v8s*)(OTb + (size_t)c * 4096 + qc * 8) = v;
  }
}

// =====================================================================
extern "C" void kernel_launch(void* const* d_in, const int* in_sizes, int n_in,
                              void* d_out, int out_size, void* d_ws, size_t ws_size,
                              hipStream_t stream) {
  (void)in_sizes; (void)n_in; (void)out_size; (void)ws_size;
  const float* x = (const float*)d_in[0];
  const float* sup = (const float*)d_in[1];
  const int* amask = (const int*)d_in[2];
  const float* Wv = (const float*)d_in[3];
  const float* Wp = (const float*)d_in[4];
  const float* bp = (const float*)d_in[5];
  float* out = (float*)d_out;

  char* ws = (char*)d_ws;
  unsigned short* QKb = (unsigned short*)ws;                      // 32768x512 bf16
  unsigned short* KT = (unsigned short*)(ws + (size_t)33554432);  // [4][512][4096]
  unsigned short* OT = (unsigned short*)(ws + (size_t)50331648);  // [4][512][4096]
  unsigned short* Kb = QKb + (size_t)16384 * 512;

  gemm_bt_kernel<0><<<dim3(1024), dim3(256), 0, stream>>>(
      x, sup, 16384, nullptr, Wv, nullptr, QKb, nullptr, 0.125f);
  transpose_k<<<dim3(64, 8, 4), dim3(256), 0, stream>>>(Kb, amask, KT);
  attn_kernel<<<dim3(512), dim3(256), 0, stream>>>(QKb, Kb, KT, OT);
  gemm_bt_kernel<1><<<dim3(512), dim3(256), 0, stream>>>(
      nullptr, nullptr, 0, OT, Wp, bp, nullptr, out, 1.0f);
}

// Round 5
// 490.884 us; speedup vs baseline: 2.0701x; 2.0701x over previous
//
#include <hip/hip_runtime.h>

typedef short v8s __attribute__((ext_vector_type(8)));
typedef float v4f __attribute__((ext_vector_type(4)));

#define AS1 __attribute__((address_space(1)))
#define AS3 __attribute__((address_space(3)))

__device__ __forceinline__ void gload_lds16(const void* g, void* l) {
  __builtin_amdgcn_global_load_lds((const AS1 unsigned*)g, (AS3 unsigned*)l, 16, 0, 0);
}

__device__ __forceinline__ unsigned short f2bf(float f) {
  union { float f; unsigned u; } x; x.f = f;
  unsigned r = x.u + 0x7fffu + ((x.u >> 16) & 1u);
  return (unsigned short)(r >> 16);
}

__device__ __forceinline__ void cvt16(const float* __restrict__ src, unsigned short* dst) {
  const float4* p = (const float4*)src;
  float4 a = p[0], b = p[1], c = p[2], d = p[3];
  dst[0] = f2bf(a.x);  dst[1] = f2bf(a.y);  dst[2] = f2bf(a.z);  dst[3] = f2bf(a.w);
  dst[4] = f2bf(b.x);  dst[5] = f2bf(b.y);  dst[6] = f2bf(b.z);  dst[7] = f2bf(b.w);
  dst[8] = f2bf(c.x);  dst[9] = f2bf(c.y);  dst[10] = f2bf(c.z); dst[11] = f2bf(c.w);
  dst[12] = f2bf(d.x); dst[13] = f2bf(d.y); dst[14] = f2bf(d.z); dst[15] = f2bf(d.w);
}

// =====================================================================
// GEMM: C[M,512] = A[M,512] @ W[512,512]^T   (BM=BN=128, BK=32, 4 waves)
// MODE 0: A = fp32 (x rows [0,rows0) then support), C = bf16, Q-rows scaled.
// MODE 1: A = bf16 (OT flat), C = fp32 + bias.
// =====================================================================
template <int MODE>
__launch_bounds__(256)
__global__ void gemm_bt_kernel(const float* __restrict__ A0,
                               const float* __restrict__ A1, int rows0,
                               const unsigned short* __restrict__ Abf,
                               const float* __restrict__ Wsrc,
                               const float* __restrict__ bias,
                               unsigned short* __restrict__ Cb,
                               float* __restrict__ Cf, float scale) {
  __shared__ __align__(16) char smem[(MODE == 1) ? 65536 : 32768];
  const int tid = threadIdx.x;
  const int wave = tid >> 6, lane = tid & 63, lr = lane & 15, lg = lane >> 4;
  const int mb = blockIdx.x >> 2, nb = blockIdx.x & 3;
  const int wr = wave >> 1, wc = wave & 1;

  v4f acc[4][4];
#pragma unroll
  for (int i = 0; i < 4; ++i)
#pragma unroll
    for (int j = 0; j < 4; ++j) acc[i][j] = (v4f){0.f, 0.f, 0.f, 0.f};

  const int srow = tid >> 1, kh = tid & 1;
  const size_t arow = (size_t)mb * 128 + srow;
  const float* asrcf = nullptr;
  const unsigned short* asrcb = nullptr;
  if constexpr (MODE == 0) {
    asrcf = (arow < (size_t)rows0) ? (A0 + arow * 512) : (A1 + (arow - (size_t)rows0) * 512);
  } else {
    asrcb = Abf + arow * 512;
  }
  const float* bsrcf = Wsrc + ((size_t)nb * 128 + srow) * 512;
  const int wa0 = srow * 64 + ((kh * 32) ^ ((srow & 3) << 4));
  const int wa1 = srow * 64 + (((kh * 32) + 16) ^ ((srow & 3) << 4));

  for (int kt = 0; kt < 16; ++kt) {
    const int kbase = kt * 32 + kh * 16;
    __syncthreads();
    unsigned short ta[16], tb[16];
    if constexpr (MODE == 0) {
      cvt16(asrcf + kbase, ta);
    } else {
      const v8s* ap = (const v8s*)(asrcb + kbase);
      *(v8s*)&ta[0] = ap[0];
      *(v8s*)&ta[8] = ap[1];
    }
    cvt16(bsrcf + kbase, tb);
    *(v8s*)&smem[wa0] = *(const v8s*)&ta[0];
    *(v8s*)&smem[wa1] = *(const v8s*)&ta[8];
    *(v8s*)&smem[8192 + wa0] = *(const v8s*)&tb[0];
    *(v8s*)&smem[8192 + wa1] = *(const v8s*)&tb[8];
    __syncthreads();

    v8s af[4], bfr[4];
    const int fo = (lg * 16) ^ ((lr & 3) << 4);
#pragma unroll
    for (int mi = 0; mi < 4; ++mi)
      af[mi] = *(const v8s*)&smem[(wr * 64 + mi * 16 + lr) * 64 + fo];
#pragma unroll
    for (int ni = 0; ni < 4; ++ni)
      bfr[ni] = *(const v8s*)&smem[8192 + (wc * 64 + ni * 16 + lr) * 64 + fo];
#pragma unroll
    for (int mi = 0; mi < 4; ++mi)
#pragma unroll
      for (int ni = 0; ni < 4; ++ni)
        acc[mi][ni] = __builtin_amdgcn_mfma_f32_16x16x32_bf16(bfr[ni], af[mi], acc[mi][ni], 0, 0, 0);
  }

  __syncthreads();
  if constexpr (MODE == 0) {
#pragma unroll
    for (int mi = 0; mi < 4; ++mi) {
      const int ml = wr * 64 + mi * 16 + lr;
      const float sc = ((size_t)mb * 128 + ml < (size_t)rows0) ? scale : 1.0f;
#pragma unroll
      for (int ni = 0; ni < 4; ++ni) {
        const int nl = wc * 64 + ni * 16 + lg * 4;
        ushort4 pk;
        pk.x = f2bf(acc[mi][ni][0] * sc);
        pk.y = f2bf(acc[mi][ni][1] * sc);
        pk.z = f2bf(acc[mi][ni][2] * sc);
        pk.w = f2bf(acc[mi][ni][3] * sc);
        *(ushort4*)&smem[ml * 256 + ((nl * 2) ^ ((ml & 7) << 4))] = pk;
      }
    }
    __syncthreads();
#pragma unroll
    for (int p = 0; p < 8; ++p) {
      const int row = p * 16 + (tid >> 4);
      const int off = (tid & 15) * 16;
      v8s v = *(const v8s*)&smem[row * 256 + (off ^ ((row & 7) << 4))];
      *(v8s*)(Cb + ((size_t)mb * 128 + row) * 512 + nb * 128 + (tid & 15) * 8) = v;
    }
  } else {
#pragma unroll
    for (int mi = 0; mi < 4; ++mi) {
      const int ml = wr * 64 + mi * 16 + lr;
#pragma unroll
      for (int ni = 0; ni < 4; ++ni) {
        const int nl = wc * 64 + ni * 16 + lg * 4;
        *(float4*)&smem[ml * 512 + ((nl * 4) ^ ((ml & 7) << 4))] =
            (float4){acc[mi][ni][0], acc[mi][ni][1], acc[mi][ni][2], acc[mi][ni][3]};
      }
    }
    __syncthreads();
    const float4 bb = *(const float4*)(bias + nb * 128 + (tid & 31) * 4);
#pragma unroll
    for (int p = 0; p < 16; ++p) {
      const int row = p * 8 + (tid >> 5);
      const int off = (tid & 31) * 16;
      float4 v = *(const float4*)&smem[row * 512 + (off ^ ((row & 7) << 4))];
      v.x += bb.x; v.y += bb.y; v.z += bb.z; v.w += bb.w;
      *(float4*)(Cf + ((size_t)mb * 128 + row) * 512 + nb * 128 + (tid & 31) * 4) = v;
    }
  }
}

// =====================================================================
// Transpose: Kb [B*4096,512] bf16 -> KT [B][512][4096] bf16, with the
// post-softmax key mask folded in (KT is only used as V; zeroing V rows
// for masked keys == zeroing P columns; lsum stays unmasked per ref).
// =====================================================================
__global__ __launch_bounds__(256) void transpose_k(const unsigned short* __restrict__ Kb,
                                                   const int* __restrict__ amask,
                                                   unsigned short* __restrict__ KT) {
  __shared__ unsigned short tile[64][65];
  const int b = blockIdx.z, cb = blockIdx.y * 64, mb = blockIdx.x * 64;
  const int tid = threadIdx.x;
#pragma unroll
  for (int i = 0; i < 16; ++i) {
    const int e = i * 256 + tid;
    const int ml = e >> 6, cl = e & 63;
    tile[ml][cl] = Kb[((size_t)b * 4096 + mb + ml) * 512 + cb + cl];
  }
  __syncthreads();
#pragma unroll
  for (int i = 0; i < 16; ++i) {
    const int e = i * 256 + tid;
    const int cl = e >> 6, ml = e & 63;
    const unsigned short v = amask[mb + ml] ? tile[ml][cl] : (unsigned short)0;
    KT[((size_t)b * 512 + cb + cl) * 4096 + mb + ml] = v;
  }
}

// =====================================================================
// Flash attention v5: R1's proven 4-wave math + async double-buffered
// staging. All 4 waves issue global_load_lds (16B, pre-swizzled global
// source, linear LDS dest) for iter it+1 right after the single barrier,
// then compute iter it from the other buffer. 1 barrier/iter.
// LDS: buf0 K@0 VT@32768, buf1 K@65536 VT@98304, P@131072 (1KB/wave).
// Epilogue O-bounce reuses [0,64KB).
// =====================================================================
__launch_bounds__(256)
__global__ void attn_kernel(const unsigned short* __restrict__ Qb,
                            const unsigned short* __restrict__ Kall,
                            const unsigned short* __restrict__ KT,
                            unsigned short* __restrict__ OT) {
  __shared__ __align__(16) char smem[135168];
  const int tid = threadIdx.x, wave = tid >> 6, lane = tid & 63;
  const int lr = lane & 15, lg = lane >> 4;
  const int orig = (blockIdx.x & 7) * 32 + (blockIdx.x >> 3);  // XCD-chunked
  const int b = orig >> 6;
  const int qb0 = (orig & 63) * 64;
  const char* Kbyte = (const char*)(Kall + (size_t)b * 4096 * 512);
  const char* KTbyte = (const char*)(KT + (size_t)b * 512 * 4096);

  // staging address precompute (R2-validated formulas)
  const int kLaneOff = lane * 16;
  // VT: lane covers c = wave*128 + i*16 + (lane>>2); row-swizzle term is
  // ((c>>1)&3) = ((lane>>3)&3) (i*16>>1 ≡ 0 mod 4, wave*128>>1 ≡ 0 mod 4)
  const size_t vtLaneBase = (size_t)(wave * 128 + (lane >> 2)) * 8192 +
                            (size_t)(((lane & 3) * 16) ^ (((lane >> 3) & 3) << 4));

  auto stage = [&](int kb, int buf) {
    char* ldsK = &smem[buf * 65536];
    char* ldsV = &smem[buf * 65536 + 32768];
    const char* ksrc = Kbyte + ((size_t)kb + wave * 8) * 1024;
#pragma unroll
    for (int i = 0; i < 8; ++i)
      gload_lds16(ksrc + (size_t)i * 1024 + (size_t)(kLaneOff ^ (i << 4)),
                  ldsK + (wave * 8 + i) * 1024);
    const char* vsrc = KTbyte + (size_t)kb * 2 + vtLaneBase;
#pragma unroll
    for (int i = 0; i < 8; ++i)
      gload_lds16(vsrc + (size_t)i * 131072, ldsV + wave * 8192 + i * 1024);
  };

  // Q frags: lane holds row (qb0 + wave*16 + lr), 8 elems at cs*32+lg*8
  const unsigned short* Qrow = Qb + ((size_t)b * 4096 + qb0 + wave * 16 + lr) * 512;
  v8s qf[16];
#pragma unroll
  for (int cs = 0; cs < 16; ++cs) qf[cs] = *(const v8s*)(Qrow + cs * 32 + lg * 8);

  v4f o[32];
#pragma unroll
  for (int i = 0; i < 32; ++i) o[i] = (v4f){0.f, 0.f, 0.f, 0.f};
  float mrun[4] = {-3e38f, -3e38f, -3e38f, -3e38f};
  float lsum[4] = {0.f, 0.f, 0.f, 0.f};
  const int Pbase = 131072 + wave * 1024;

  stage(0, 0);

#pragma unroll 1
  for (int it = 0; it < 128; ++it) {
    const int cur = it & 1;
    __syncthreads();  // drains stage(it) loads; prev compute reads done
    if (it + 1 < 128) stage((it + 1) * 32, cur ^ 1);

    const char* bK = &smem[cur * 65536];
    const char* bVT = &smem[cur * 65536 + 32768];
    // ---- QK^T: S frag col=key(lr), rows=q(lg*4+r)
    v4f s0 = (v4f){0.f, 0.f, 0.f, 0.f}, s1 = (v4f){0.f, 0.f, 0.f, 0.f};
    const int kswz = (lr & 7) << 4;
    __builtin_amdgcn_s_setprio(1);
#pragma unroll
    for (int cs = 0; cs < 16; ++cs) {
      const int yb = cs * 64 + lg * 16;
      v8s k0 = *(const v8s*)&bK[lr * 1024 + (yb ^ kswz)];
      v8s k1 = *(const v8s*)&bK[(lr + 16) * 1024 + (yb ^ kswz)];
      s0 = __builtin_amdgcn_mfma_f32_16x16x32_bf16(qf[cs], k0, s0, 0, 0, 0);
      s1 = __builtin_amdgcn_mfma_f32_16x16x32_bf16(qf[cs], k1, s1, 0, 0, 0);
    }
    __builtin_amdgcn_s_setprio(0);

    // ---- online softmax (deferred rescale, THR=8)
    float tmax[4];
#pragma unroll
    for (int r = 0; r < 4; ++r) tmax[r] = fmaxf(s0[r], s1[r]);
#pragma unroll
    for (int msk = 1; msk < 16; msk <<= 1)
#pragma unroll
      for (int r = 0; r < 4; ++r) tmax[r] = fmaxf(tmax[r], __shfl_xor(tmax[r], msk));
    bool need = false;
#pragma unroll
    for (int r = 0; r < 4; ++r) need = need || (tmax[r] > mrun[r] + 8.0f);
    if (__any(need)) {
      v4f sfv;
#pragma unroll
      for (int r = 0; r < 4; ++r) {
        const float nm = fmaxf(mrun[r], tmax[r]);
        const float sf = __expf(mrun[r] - nm);
        lsum[r] *= sf;
        mrun[r] = nm;
        sfv[r] = sf;
      }
#pragma unroll
      for (int i = 0; i < 32; ++i) o[i] *= sfv;
    }
#pragma unroll
    for (int r = 0; r < 4; ++r) {
      const float p0 = __expf(s0[r] - mrun[r]);
      const float p1 = __expf(s1[r] - mrun[r]);
      lsum[r] += p0 + p1;  // unmasked denominator (per reference)
      const int q = lg * 4 + r;
      *(unsigned short*)&smem[Pbase + q * 64 + lr * 2] = f2bf(p0);
      *(unsigned short*)&smem[Pbase + q * 64 + 32 + lr * 2] = f2bf(p1);
    }
    // ---- PV (V pre-masked in KT): A=P, B=VT frags
    v8s pf = *(const v8s*)&smem[Pbase + lr * 64 + lg * 16];
    __builtin_amdgcn_s_setprio(1);
#pragma unroll
    for (int ct = 0; ct < 32; ++ct) {
      const int c = ct * 16 + lr;
      v8s vf = *(const v8s*)&bVT[c * 64 + ((lg * 16) ^ (((c >> 1) & 3) << 4))];
      o[ct] = __builtin_amdgcn_mfma_f32_16x16x32_bf16(pf, vf, o[ct], 0, 0, 0);
    }
    __builtin_amdgcn_s_setprio(0);
  }

  // ---- finalize: reduce lsum across the 16 key-lanes, normalize
#pragma unroll
  for (int msk = 1; msk < 16; msk <<= 1)
#pragma unroll
    for (int r = 0; r < 4; ++r) lsum[r] += __shfl_xor(lsum[r], msk);
  float inv[4];
#pragma unroll
  for (int r = 0; r < 4; ++r) inv[r] = 1.0f / lsum[r];

  __syncthreads();  // everyone done with loop LDS
  const int obase = wave * 16384;
#pragma unroll
  for (int ct = 0; ct < 32; ++ct)
#pragma unroll
    for (int r = 0; r < 4; ++r)
      *(unsigned short*)&smem[obase + (ct * 16 + lr) * 32 + (lg * 4 + r) * 2] =
          f2bf(o[ct][r] * inv[r]);
  __syncthreads();
  unsigned short* OTb = OT + (size_t)b * 512 * 4096 + qb0;
#pragma unroll
  for (int p = 0; p < 32; ++p) {
    const int c = p * 16 + (tid >> 4);
    const int q4 = (tid & 15) * 4;
    const int w = q4 >> 4, ql = q4 & 15;
    ushort4 pk = *(const ushort4*)&smem[w * 16384 + c * 32 + ql * 2];
    *(ushort4*)(OTb + (size_t)c * 4096 + q4) = pk;
  }
}

// =====================================================================
extern "C" void kernel_launch(void* const* d_in, const int* in_sizes, int n_in,
                              void* d_out, int out_size, void* d_ws, size_t ws_size,
                              hipStream_t stream) {
  (void)in_sizes; (void)n_in; (void)out_size; (void)ws_size;
  const float* x = (const float*)d_in[0];
  const float* sup = (const float*)d_in[1];
  const int* amask = (const int*)d_in[2];
  const float* Wv = (const float*)d_in[3];
  const float* Wp = (const float*)d_in[4];
  const float* bp = (const float*)d_in[5];
  float* out = (float*)d_out;

  char* ws = (char*)d_ws;
  unsigned short* QKb = (unsigned short*)ws;                      // 32768x512 bf16
  unsigned short* KT = (unsigned short*)(ws + (size_t)33554432);  // [4][512][4096]
  unsigned short* OT = (unsigned short*)(ws + (size_t)50331648);  // [4][512][4096]
  unsigned short* Kb = QKb + (size_t)16384 * 512;

  gemm_bt_kernel<0><<<dim3(1024), dim3(256), 0, stream>>>(
      x, sup, 16384, nullptr, Wv, nullptr, QKb, nullptr, 0.125f);
  transpose_k<<<dim3(64, 8, 4), dim3(256), 0, stream>>>(Kb, amask, KT);
  attn_kernel<<<dim3(256), dim3(256), 0, stream>>>(QKb, Kb, KT, OT);
  gemm_bt_kernel<1><<<dim3(512), dim3(256), 0, stream>>>(
      nullptr, nullptr, 0, OT, Wp, bp, nullptr, out, 1.0f);
}